// Round 1
// baseline (1660.234 us; speedup 1.0000x reference)
//
#include <hip/hip_runtime.h>

// GCN: h1 = relu(gcnconv(x, W1, b1)); h2 = relu(gcnconv(h1, W2, b2));
// out = sigmoid(mean(h2, axis=0) @ Wf + bf)
// gcnconv(x,W,b): h = x@W; deg = indeg(dst)+1; dinv = rsqrt(deg);
//   out[d] = sum_{e:dst=d} h[src_e]*dinv[src]*dinv[dst] + h[d]*dinv[d]^2 + b

constexpr int HID = 64;

// ---- degree histogram (float counts are exact for < 2^24) ----
__global__ void deg_kernel(const int* __restrict__ dst, float* __restrict__ deg, int ne) {
    int i = blockIdx.x * blockDim.x + threadIdx.x;
    int stride = gridDim.x * blockDim.x;
    for (; i < ne; i += stride) atomicAdd(&deg[dst[i]], 1.0f);
}

__global__ void dinv_kernel(float* __restrict__ deg, int n) {
    int i = blockIdx.x * blockDim.x + threadIdx.x;
    if (i < n) deg[i] = rsqrtf(deg[i] + 1.0f);
}

// ---- GEMM: out[n x 64] = A[n x K] @ W[K x 64]; 16 rows/block, 4 rows/thread ----
template <int K>
__global__ __launch_bounds__(256) void gemm_kernel(const float* __restrict__ A,
                                                   const float* __restrict__ W,
                                                   float* __restrict__ out, int n) {
    __shared__ float xs[16][K];
    const int t = threadIdx.x;
    const int row0 = blockIdx.x * 16;

    if (row0 + 16 <= n) {
        const float4* Ap = reinterpret_cast<const float4*>(A + (size_t)row0 * K);
        float4* xsv = reinterpret_cast<float4*>(&xs[0][0]);
        #pragma unroll
        for (int i = t; i < 16 * K / 4; i += 256) xsv[i] = Ap[i];
    } else {
        for (int i = t; i < 16 * K; i += 256) {
            int r = i / K;
            if (row0 + r < n) (&xs[0][0])[i] = A[(size_t)row0 * K + i];
        }
    }
    __syncthreads();

    const int c = t & 63;        // output column
    const int rg = t >> 6;       // row group 0..3 (wave-uniform)
    float acc[4] = {0.f, 0.f, 0.f, 0.f};
    #pragma unroll 4
    for (int k = 0; k < K; ++k) {
        float w = W[k * HID + c];          // 256B coalesced, L1-resident
        #pragma unroll
        for (int j = 0; j < 4; ++j) acc[j] += xs[rg + 4 * j][k] * w;  // LDS broadcast
    }
    #pragma unroll
    for (int j = 0; j < 4; ++j) {
        int r = row0 + rg + 4 * j;
        if (r < n) out[(size_t)r * HID + c] = acc[j];
    }
}

// ---- edge aggregation: one wave per edge, lane = feature ----
__global__ __launch_bounds__(256) void aggregate_kernel(const float* __restrict__ h,
                                                        const int* __restrict__ src,
                                                        const int* __restrict__ dst,
                                                        const float* __restrict__ dinv,
                                                        float* __restrict__ out, int ne) {
    size_t t = (size_t)blockIdx.x * blockDim.x + threadIdx.x;
    int e = (int)(t >> 6);
    int f = (int)(t & 63);
    if (e >= ne) return;
    int s = src[e];   // wave-uniform
    int d = dst[e];   // wave-uniform
    float norm = dinv[s] * dinv[d];
    atomicAdd(&out[(size_t)d * HID + f], h[(size_t)s * HID + f] * norm);
}

// ---- finalize layer 1: h1 = relu(agg + h*dinv^2 + b), in place over h ----
__global__ void finalize1_kernel(float* __restrict__ h, const float* __restrict__ agg,
                                 const float* __restrict__ dinv, const float* __restrict__ b,
                                 int n) {
    size_t i = (size_t)blockIdx.x * blockDim.x + threadIdx.x;
    if (i >= (size_t)n * HID) return;
    int node = (int)(i >> 6);
    float di = dinv[node];
    float v = agg[i] + h[i] * di * di + b[i & 63];
    h[i] = fmaxf(v, 0.f);
}

// ---- finalize layer 2 fused with graph-mean partial reduction ----
__global__ __launch_bounds__(256) void finalize2_reduce_kernel(const float* __restrict__ hpre,
                                                               const float* __restrict__ agg,
                                                               const float* __restrict__ dinv,
                                                               const float* __restrict__ b,
                                                               float* __restrict__ gsum, int n) {
    __shared__ float sred[256];
    const int t = threadIdx.x;
    const int c = t & 63;
    const size_t total = (size_t)n * HID;
    const size_t stride = (size_t)gridDim.x * blockDim.x;  // multiple of 64 -> col invariant
    float acc = 0.f;
    for (size_t i = (size_t)blockIdx.x * blockDim.x + t; i < total; i += stride) {
        int node = (int)(i >> 6);
        float di = dinv[node];
        float v = agg[i] + hpre[i] * di * di + b[c];
        acc += fmaxf(v, 0.f);
    }
    sred[t] = acc;
    __syncthreads();
    if (t < 64) atomicAdd(&gsum[c], sred[t] + sred[t + 64] + sred[t + 128] + sred[t + 192]);
}

// ---- final: out = sigmoid(dot(gsum/n, Wf) + bf) ----
__global__ void final_kernel(const float* __restrict__ gsum, const float* __restrict__ Wf,
                             const float* __restrict__ bf, float* __restrict__ out, int n) {
    int lane = threadIdx.x;
    float v = (gsum[lane] / (float)n) * Wf[lane];
    #pragma unroll
    for (int off = 32; off; off >>= 1) v += __shfl_down(v, off);
    if (lane == 0) out[0] = 1.f / (1.f + expf(-(v + bf[0])));
}

extern "C" void kernel_launch(void* const* d_in, const int* in_sizes, int n_in,
                              void* d_out, int out_size, void* d_ws, size_t ws_size,
                              hipStream_t stream) {
    const float* x  = (const float*)d_in[0];
    const int*   ei = (const int*)d_in[1];
    const float* W1 = (const float*)d_in[2];
    const float* b1 = (const float*)d_in[3];
    const float* W2 = (const float*)d_in[4];
    const float* b2 = (const float*)d_in[5];
    const float* Wf = (const float*)d_in[6];
    const float* bf = (const float*)d_in[7];
    float* out = (float*)d_out;

    const int n  = in_sizes[0] / 256;   // 100000
    const int ne = in_sizes[1] / 2;     // 3200000
    const int* srcp = ei;
    const int* dstp = ei + ne;

    float* ws   = (float*)d_ws;
    float* dinv = ws;                       // n floats (deg -> dinv in place)
    float* gsum = ws + n;                   // 64 floats
    float* bufA = ws + n + 64;              // n*64
    float* bufB = bufA + (size_t)n * HID;   // n*64

    // zero deg + gsum
    hipMemsetAsync(dinv, 0, (size_t)(n + 64) * sizeof(float), stream);
    deg_kernel<<<2048, 256, 0, stream>>>(dstp, dinv, ne);
    dinv_kernel<<<(n + 255) / 256, 256, 0, stream>>>(dinv, n);

    // layer 1
    gemm_kernel<256><<<(n + 15) / 16, 256, 0, stream>>>(x, W1, bufA, n);
    hipMemsetAsync(bufB, 0, (size_t)n * HID * sizeof(float), stream);
    {
        size_t threads = (size_t)ne * 64;
        aggregate_kernel<<<(int)((threads + 255) / 256), 256, 0, stream>>>(bufA, srcp, dstp, dinv, bufB, ne);
    }
    finalize1_kernel<<<(int)(((size_t)n * HID + 255) / 256), 256, 0, stream>>>(bufA, bufB, dinv, b1, n);

    // layer 2
    gemm_kernel<64><<<(n + 15) / 16, 256, 0, stream>>>(bufA, W2, bufB, n);
    hipMemsetAsync(bufA, 0, (size_t)n * HID * sizeof(float), stream);
    {
        size_t threads = (size_t)ne * 64;
        aggregate_kernel<<<(int)((threads + 255) / 256), 256, 0, stream>>>(bufB, srcp, dstp, dinv, bufA, ne);
    }
    finalize2_reduce_kernel<<<2048, 256, 0, stream>>>(bufB, bufA, dinv, b2, gsum, n);

    final_kernel<<<1, 64, 0, stream>>>(gsum, Wf, bf, out, n);
}

// Round 2
// 918.907 us; speedup vs baseline: 1.8067x; 1.8067x over previous
//
#include <hip/hip_runtime.h>

// GCN: h1 = relu(gcnconv(x, W1, b1)); h2 = relu(gcnconv(h1, W2, b2));
// out = sigmoid(mean(h2, axis=0) @ Wf + bf)
// gcnconv(x,W,b): h = x@W; dinv = rsqrt(indeg(dst)+1);
//   out[d] = dinv[d] * ( sum_{e:dst=d} hp[src_e] + hp[d] ) + b,  hp = h * dinv (rowwise)
//
// Strategy: build CSR (dst-sorted src lists) on device once; aggregation is
// gather-based (one wave per node, lane = feature) -> no f32 atomics.

constexpr int HID = 64;
constexpr int NBLK2 = 1024;   // blocks for fused layer-2 agg + mean reduction

// ---------------- CSR build ----------------
__global__ void count_kernel(const int* __restrict__ dst, int* __restrict__ cnt, int ne) {
    int i = blockIdx.x * blockDim.x + threadIdx.x, st = gridDim.x * blockDim.x;
    for (; i < ne; i += st) atomicAdd(&cnt[dst[i]], 1);
}

__global__ void dinv_kernel(const int* __restrict__ cnt, float* __restrict__ dinv, int n) {
    int i = blockIdx.x * blockDim.x + threadIdx.x;
    if (i < n) dinv[i] = rsqrtf((float)cnt[i] + 1.0f);
}

// per-block (1024 elems) sums
__global__ __launch_bounds__(256) void block_sums_kernel(const int* __restrict__ cnt,
                                                         int* __restrict__ bsum, int n) {
    __shared__ int s[256];
    int t = threadIdx.x;
    int base = blockIdx.x * 1024 + t * 4;
    int a = 0;
    #pragma unroll
    for (int j = 0; j < 4; ++j) { int i = base + j; if (i < n) a += cnt[i]; }
    s[t] = a; __syncthreads();
    for (int off = 128; off; off >>= 1) { if (t < off) s[t] += s[t + off]; __syncthreads(); }
    if (t == 0) bsum[blockIdx.x] = s[0];
}

__global__ void scan_bsums_kernel(const int* __restrict__ bsum, int* __restrict__ bscan, int nb) {
    if (threadIdx.x == 0 && blockIdx.x == 0) {
        int r = 0;
        for (int i = 0; i < nb; ++i) { bscan[i] = r; r += bsum[i]; }
    }
}

// exclusive scan -> rowptr[0..n]
__global__ __launch_bounds__(256) void scan_blocks_kernel(const int* __restrict__ cnt,
                                                          const int* __restrict__ bscan,
                                                          int* __restrict__ rowptr, int n) {
    __shared__ int ssc[256];
    int t = threadIdx.x;
    int base = blockIdx.x * 1024 + t * 4;
    int c[4];
    #pragma unroll
    for (int j = 0; j < 4; ++j) { int i = base + j; c[j] = (i < n) ? cnt[i] : 0; }
    int tsum = c[0] + c[1] + c[2] + c[3];
    ssc[t] = tsum; __syncthreads();
    int run = tsum;
    for (int off = 1; off < 256; off <<= 1) {
        int v = (t >= off) ? ssc[t - off] : 0;
        __syncthreads();
        run += v; ssc[t] = run;
        __syncthreads();
    }
    int ex = bscan[blockIdx.x] + run - tsum;   // exclusive prefix for this thread's 4 elems
    #pragma unroll
    for (int j = 0; j < 4; ++j) {
        int i = base + j;
        if (i <= n) rowptr[i] = ex;
        ex += c[j];
    }
}

// scatter src into CSR slots; mutates rowptr into end-pointers
__global__ void scatter_kernel(const int* __restrict__ src, const int* __restrict__ dst,
                               int* __restrict__ rowptr, int* __restrict__ eidx, int ne) {
    int i = blockIdx.x * blockDim.x + threadIdx.x, st = gridDim.x * blockDim.x;
    for (; i < ne; i += st) {
        int pos = atomicAdd(&rowptr[dst[i]], 1);
        eidx[pos] = src[i];
    }
}

// ---------------- GEMM with dinv row-scale epilogue ----------------
// out[r][c] = (A[r,:] @ W[:,c]) * dinv[r]   (dinv==nullptr -> no scale)
template <int K>
__global__ __launch_bounds__(256) void gemm_scale_kernel(const float* __restrict__ A,
                                                         const float* __restrict__ W,
                                                         const float* __restrict__ dinv,
                                                         float* __restrict__ out, int n) {
    __shared__ float xs[16][K];
    const int t = threadIdx.x;
    const int row0 = blockIdx.x * 16;

    if (row0 + 16 <= n) {
        const float4* Ap = reinterpret_cast<const float4*>(A + (size_t)row0 * K);
        float4* xsv = reinterpret_cast<float4*>(&xs[0][0]);
        #pragma unroll
        for (int i = t; i < 16 * K / 4; i += 256) xsv[i] = Ap[i];
    } else {
        for (int i = t; i < 16 * K; i += 256) {
            int r = i / K;
            if (row0 + r < n) (&xs[0][0])[i] = A[(size_t)row0 * K + i];
        }
    }
    __syncthreads();

    const int c = t & 63;
    const int rg = t >> 6;
    float acc[4] = {0.f, 0.f, 0.f, 0.f};
    #pragma unroll 4
    for (int k = 0; k < K; ++k) {
        float w = W[k * HID + c];
        #pragma unroll
        for (int j = 0; j < 4; ++j) acc[j] += xs[rg + 4 * j][k] * w;
    }
    #pragma unroll
    for (int j = 0; j < 4; ++j) {
        int r = row0 + rg + 4 * j;
        if (r < n) {
            float s = dinv ? dinv[r] : 1.0f;
            out[(size_t)r * HID + c] = acc[j] * s;
        }
    }
}

// ---------------- CSR gather aggregation (layer 1): writes relu'd h1 ----------------
__global__ __launch_bounds__(256) void agg_csr_kernel(const float* __restrict__ hp,
                                                      const int* __restrict__ eidx,
                                                      const int* __restrict__ rowend,
                                                      const float* __restrict__ dinv,
                                                      const float* __restrict__ b,
                                                      float* __restrict__ out, int n) {
    int w = (blockIdx.x * 256 + threadIdx.x) >> 6;
    int lane = threadIdx.x & 63;
    if (w >= n) return;
    int beg = w ? rowend[w - 1] : 0;
    int end = rowend[w];
    float a0 = 0.f, a1 = 0.f, a2 = 0.f, a3 = 0.f;
    int p = beg;
    for (; p + 8 <= end; p += 8) {
        int s0 = eidx[p], s1 = eidx[p+1], s2 = eidx[p+2], s3 = eidx[p+3];
        int s4 = eidx[p+4], s5 = eidx[p+5], s6 = eidx[p+6], s7 = eidx[p+7];
        a0 += hp[(size_t)s0 * 64 + lane]; a1 += hp[(size_t)s1 * 64 + lane];
        a2 += hp[(size_t)s2 * 64 + lane]; a3 += hp[(size_t)s3 * 64 + lane];
        a0 += hp[(size_t)s4 * 64 + lane]; a1 += hp[(size_t)s5 * 64 + lane];
        a2 += hp[(size_t)s6 * 64 + lane]; a3 += hp[(size_t)s7 * 64 + lane];
    }
    for (; p < end; ++p) a0 += hp[(size_t)eidx[p] * 64 + lane];
    float acc = (a0 + a1) + (a2 + a3);
    float dv = dinv[w];
    float v = dv * (acc + hp[(size_t)w * 64 + lane]) + b[lane];
    out[(size_t)w * 64 + lane] = fmaxf(v, 0.f);
}

// ---------------- layer 2: CSR aggregation fused with graph-mean partials ----------------
__global__ __launch_bounds__(256) void agg_csr_reduce_kernel(const float* __restrict__ hp,
                                                             const int* __restrict__ eidx,
                                                             const int* __restrict__ rowend,
                                                             const float* __restrict__ dinv,
                                                             const float* __restrict__ b,
                                                             float* __restrict__ partials, int n) {
    __shared__ float sred[256];
    int t = threadIdx.x, lane = t & 63;
    int wid = (blockIdx.x * 256 + t) >> 6;
    int wstride = gridDim.x * 4;
    float bl = b[lane];
    float tacc = 0.f;
    for (int w = wid; w < n; w += wstride) {
        int beg = w ? rowend[w - 1] : 0;
        int end = rowend[w];
        float a0 = 0.f, a1 = 0.f, a2 = 0.f, a3 = 0.f;
        int p = beg;
        for (; p + 8 <= end; p += 8) {
            int s0 = eidx[p], s1 = eidx[p+1], s2 = eidx[p+2], s3 = eidx[p+3];
            int s4 = eidx[p+4], s5 = eidx[p+5], s6 = eidx[p+6], s7 = eidx[p+7];
            a0 += hp[(size_t)s0 * 64 + lane]; a1 += hp[(size_t)s1 * 64 + lane];
            a2 += hp[(size_t)s2 * 64 + lane]; a3 += hp[(size_t)s3 * 64 + lane];
            a0 += hp[(size_t)s4 * 64 + lane]; a1 += hp[(size_t)s5 * 64 + lane];
            a2 += hp[(size_t)s6 * 64 + lane]; a3 += hp[(size_t)s7 * 64 + lane];
        }
        for (; p < end; ++p) a0 += hp[(size_t)eidx[p] * 64 + lane];
        float acc = (a0 + a1) + (a2 + a3);
        float dv = dinv[w];
        tacc += fmaxf(dv * (acc + hp[(size_t)w * 64 + lane]) + bl, 0.f);
    }
    sred[t] = tacc; __syncthreads();
    if (t < 64) partials[blockIdx.x * 64 + t] = sred[t] + sred[t + 64] + sred[t + 128] + sred[t + 192];
}

// ---------------- final: out = sigmoid(dot(mean, Wf) + bf) ----------------
__global__ void final_partials_kernel(const float* __restrict__ partials, int nblk,
                                      const float* __restrict__ Wf, const float* __restrict__ bf,
                                      float* __restrict__ out, float invn) {
    __shared__ float sred[256];
    int t = threadIdx.x, lane = t & 63, grp = t >> 6;
    float a = 0.f;
    for (int bk = grp; bk < nblk; bk += 4) a += partials[bk * 64 + lane];
    sred[t] = a; __syncthreads();
    if (t < 64) {
        float v = (sred[t] + sred[t + 64] + sred[t + 128] + sred[t + 192]) * invn * Wf[t];
        #pragma unroll
        for (int off = 32; off; off >>= 1) v += __shfl_down(v, off);
        if (t == 0) out[0] = 1.f / (1.f + expf(-(v + bf[0])));
    }
}

// ================= fallback path (atomic aggregation, ~52 MB ws) =================
__global__ void deg_f_kernel(const int* __restrict__ dst, float* __restrict__ deg, int ne) {
    int i = blockIdx.x * blockDim.x + threadIdx.x, st = gridDim.x * blockDim.x;
    for (; i < ne; i += st) atomicAdd(&deg[dst[i]], 1.0f);
}
__global__ void dinvf_kernel(float* __restrict__ deg, int n) {
    int i = blockIdx.x * blockDim.x + threadIdx.x;
    if (i < n) deg[i] = rsqrtf(deg[i] + 1.0f);
}
__global__ __launch_bounds__(256) void aggregate_atomic_kernel(const float* __restrict__ hp,
        const int* __restrict__ src, const int* __restrict__ dst,
        const float* __restrict__ dinv, float* __restrict__ out, int ne) {
    size_t t = (size_t)blockIdx.x * blockDim.x + threadIdx.x;
    int e = (int)(t >> 6), f = (int)(t & 63);
    if (e >= ne) return;
    int s = src[e], d = dst[e];
    atomicAdd(&out[(size_t)d * HID + f], hp[(size_t)s * HID + f] * dinv[d]);
}
__global__ void finalize1_fb_kernel(float* __restrict__ hp, const float* __restrict__ agg,
                                    const float* __restrict__ dinv, const float* __restrict__ b, int n) {
    size_t i = (size_t)blockIdx.x * blockDim.x + threadIdx.x;
    if (i >= (size_t)n * HID) return;
    int node = (int)(i >> 6);
    float di = dinv[node];
    hp[i] = fmaxf(agg[i] + hp[i] * di + b[i & 63], 0.f);
}
__global__ __launch_bounds__(256) void finalize2_fb_kernel(const float* __restrict__ hp,
        const float* __restrict__ agg, const float* __restrict__ dinv,
        const float* __restrict__ b, float* __restrict__ gsum, int n) {
    __shared__ float sred[256];
    const int t = threadIdx.x, c = t & 63;
    const size_t total = (size_t)n * HID;
    const size_t stride = (size_t)gridDim.x * blockDim.x;
    float acc = 0.f;
    for (size_t i = (size_t)blockIdx.x * blockDim.x + t; i < total; i += stride) {
        int node = (int)(i >> 6);
        float di = dinv[node];
        acc += fmaxf(agg[i] + hp[i] * di + b[c], 0.f);
    }
    sred[t] = acc; __syncthreads();
    if (t < 64) atomicAdd(&gsum[c], sred[t] + sred[t + 64] + sred[t + 128] + sred[t + 192]);
}
__global__ void final_gsum_kernel(const float* __restrict__ gsum, const float* __restrict__ Wf,
                                  const float* __restrict__ bf, float* __restrict__ out, int n) {
    int lane = threadIdx.x;
    float v = (gsum[lane] / (float)n) * Wf[lane];
    #pragma unroll
    for (int off = 32; off; off >>= 1) v += __shfl_down(v, off);
    if (lane == 0) out[0] = 1.f / (1.f + expf(-(v + bf[0])));
}

extern "C" void kernel_launch(void* const* d_in, const int* in_sizes, int n_in,
                              void* d_out, int out_size, void* d_ws, size_t ws_size,
                              hipStream_t stream) {
    const float* x  = (const float*)d_in[0];
    const int*   ei = (const int*)d_in[1];
    const float* W1 = (const float*)d_in[2];
    const float* b1 = (const float*)d_in[3];
    const float* W2 = (const float*)d_in[4];
    const float* b2 = (const float*)d_in[5];
    const float* Wf = (const float*)d_in[6];
    const float* bf = (const float*)d_in[7];
    float* out = (float*)d_out;

    const int n  = in_sizes[0] / 256;
    const int ne = in_sizes[1] / 2;
    const int* srcp = ei;
    const int* dstp = ei + ne;

    // ---- primary layout ----
    char* p = (char*)d_ws;
    int*   cnt    = (int*)p;   p += (size_t)n * 4;
    float* dinv   = (float*)p; p += (size_t)n * 4;
    int*   rowptr = (int*)p;   p += ((size_t)n + 4) * 4;
    int*   bsum   = (int*)p;   p += 512;
    int*   bscan  = (int*)p;   p += 512;
    int*   eidx   = (int*)p;   p += (size_t)ne * 4;
    float* parts  = (float*)p; p += (size_t)NBLK2 * 64 * 4;
    float* bufA   = (float*)p; p += (size_t)n * HID * 4;
    float* bufB   = (float*)p; p += (size_t)n * HID * 4;
    size_t need = (size_t)(p - (char*)d_ws);

    if (ws_size >= need) {
        const int NB = (n + 1023) / 1024;
        hipMemsetAsync(cnt, 0, (size_t)n * 4, stream);
        count_kernel<<<2048, 256, 0, stream>>>(dstp, cnt, ne);
        dinv_kernel<<<(n + 255) / 256, 256, 0, stream>>>(cnt, dinv, n);
        block_sums_kernel<<<NB, 256, 0, stream>>>(cnt, bsum, n);
        scan_bsums_kernel<<<1, 64, 0, stream>>>(bsum, bscan, NB);
        scan_blocks_kernel<<<NB, 256, 0, stream>>>(cnt, bscan, rowptr, n);
        scatter_kernel<<<2048, 256, 0, stream>>>(srcp, dstp, rowptr, eidx, ne);
        // rowptr is now end-pointers

        // layer 1
        gemm_scale_kernel<256><<<(n + 15) / 16, 256, 0, stream>>>(x, W1, dinv, bufA, n);
        agg_csr_kernel<<<(n + 3) / 4, 256, 0, stream>>>(bufA, eidx, rowptr, dinv, b1, bufB, n);
        // layer 2
        gemm_scale_kernel<64><<<(n + 15) / 16, 256, 0, stream>>>(bufB, W2, dinv, bufA, n);
        agg_csr_reduce_kernel<<<NBLK2, 256, 0, stream>>>(bufA, eidx, rowptr, dinv, b2, parts, n);
        final_partials_kernel<<<1, 256, 0, stream>>>(parts, NBLK2, Wf, bf, out, 1.0f / (float)n);
    } else {
        // ---- fallback: proven round-1 structure with hp pre-scale ----
        float* ws    = (float*)d_ws;
        float* dinvF = ws;
        float* gsum  = ws + n;
        float* bufAF = ws + n + 64;
        float* bufBF = bufAF + (size_t)n * HID;

        hipMemsetAsync(dinvF, 0, (size_t)(n + 64) * sizeof(float), stream);
        deg_f_kernel<<<2048, 256, 0, stream>>>(dstp, dinvF, ne);
        dinvf_kernel<<<(n + 255) / 256, 256, 0, stream>>>(dinvF, n);

        gemm_scale_kernel<256><<<(n + 15) / 16, 256, 0, stream>>>(x, W1, dinvF, bufAF, n);
        hipMemsetAsync(bufBF, 0, (size_t)n * HID * sizeof(float), stream);
        {
            size_t threads = (size_t)ne * 64;
            aggregate_atomic_kernel<<<(int)((threads + 255) / 256), 256, 0, stream>>>(bufAF, srcp, dstp, dinvF, bufBF, ne);
        }
        finalize1_fb_kernel<<<(int)(((size_t)n * HID + 255) / 256), 256, 0, stream>>>(bufAF, bufBF, dinvF, b1, n);

        gemm_scale_kernel<64><<<(n + 15) / 16, 256, 0, stream>>>(bufAF, W2, dinvF, bufBF, n);
        hipMemsetAsync(bufAF, 0, (size_t)n * HID * sizeof(float), stream);
        {
            size_t threads = (size_t)ne * 64;
            aggregate_atomic_kernel<<<(int)((threads + 255) / 256), 256, 0, stream>>>(bufBF, srcp, dstp, dinvF, bufAF, ne);
        }
        finalize2_fb_kernel<<<2048, 256, 0, stream>>>(bufBF, bufAF, dinvF, b2, gsum, n);
        final_gsum_kernel<<<1, 64, 0, stream>>>(gsum, Wf, bf, out, n);
    }
}